// Round 5
// baseline (202.593 us; speedup 1.0000x reference)
//
#include <hip/hip_runtime.h>
#include <hip/hip_bf16.h>

// Problem constants
#define B_    32
#define T_    512
#define C_    384
#define D_    1536      // C*MULT
#define H_    1024
#define L_    255       // (T-SIZE)/STRIDE + 1
#define KP_   6144      // SIZE*D
#define ND_   16

// Wave tile 128x64 (8 m-frags x 4 n-frags), BK=32 (rows = 64B = 4 x 16B chunks).
// LDS XOR swizzle: chunk_phys = chunk_log ^ ((row>>1)&3)  -> 2-way max (free).
// gemm1: BM=256 BN=128, 4 waves (2Mx2N), buf = 16KB A + 8KB B = 24KB, x3 = 72KB -> 2 blocks/CU
// gemm2: BM=256 BN=256, 8 waves (2Mx4N), buf = 16KB A + 16KB B = 32KB, x3 = 96KB, split-K x2
#define BUF1 24576
#define BUF2 32768

using f32x4 = __attribute__((ext_vector_type(4))) float;
using s16x8 = __attribute__((ext_vector_type(8))) short;

__device__ __forceinline__ void gld_lds16(const void* g, void* l) {
    __builtin_amdgcn_global_load_lds(
        (const __attribute__((address_space(1))) void*)g,
        (__attribute__((address_space(3))) void*)l,
        16, 0, 0);
}

// ------------- prep: all f32->bf16 conversions + mask/ts, one launch ----
__global__ __launch_bounds__(256) void prep(
    const float* __restrict__ sp, const float* __restrict__ we,
    const float* __restrict__ wp, const int* __restrict__ mIn,
    const int* __restrict__ tIn,
    __hip_bfloat16* __restrict__ spB, __hip_bfloat16* __restrict__ weB,
    __hip_bfloat16* __restrict__ wpB, float* __restrict__ out) {
    int id = blockIdx.x * 256 + threadIdx.x;
    const float* src; __hip_bfloat16* dst; int idx;
    if (id < 1572864)       { src = sp; dst = spB; idx = id; }
    else if (id < 3932160)  { src = we; dst = weB; idx = id - 1572864; }
    else if (id < 5505024)  { src = wp; dst = wpB; idx = id - 3932160; }
    else {
        int i = id - 5505024;
        if (i < B_ * L_) {
            int b = i / L_, l = i % L_;
            const int* mb = mIn + b * T_ + 2 * l;
            int m = mb[0] * mb[1] * mb[2] * mb[3];
            const size_t offM = (size_t)B_ * L_ * H_;
            out[offM + i] = (float)m;
            out[offM + (size_t)B_ * L_ + i] = (float)tIn[b * T_ + l];
        }
        return;
    }
    float4 v = reinterpret_cast<const float4*>(src)[idx];
    __hip_bfloat16 o[4] = {__float2bfloat16(v.x), __float2bfloat16(v.y),
                           __float2bfloat16(v.z), __float2bfloat16(v.w)};
    reinterpret_cast<ushort4*>(dst)[idx] = *reinterpret_cast<ushort4*>(o);
}

// One K=32 tile for a 128x64 wave tile: 8 A-frags, 4 B-frags, 32 MFMA in 4
// phases of 8; B[q+1] read issued under phase-q MFMAs; counted lgkm waits.
__device__ __forceinline__ void ktile32(const char* la, const char* lb,
                                        const int* aOff, const int* bOff,
                                        f32x4 (&acc)[8][4]) {
    s16x8 A[8], Bv[4];
    #pragma unroll
    for (int i = 0; i < 8; ++i) A[i] = *(const s16x8*)(la + aOff[i]);
    Bv[0] = *(const s16x8*)(lb + bOff[0]);
    Bv[1] = *(const s16x8*)(lb + bOff[1]);
    asm volatile("s_waitcnt lgkmcnt(1)" ::: "memory");
    __builtin_amdgcn_sched_barrier(0);
    __builtin_amdgcn_s_setprio(1);
    #pragma unroll
    for (int mi = 0; mi < 8; ++mi)
        acc[mi][0] = __builtin_amdgcn_mfma_f32_16x16x32_bf16(A[mi], Bv[0], acc[mi][0], 0, 0, 0);
    __builtin_amdgcn_s_setprio(0);
    Bv[2] = *(const s16x8*)(lb + bOff[2]);
    asm volatile("s_waitcnt lgkmcnt(1)" ::: "memory");
    __builtin_amdgcn_sched_barrier(0);
    __builtin_amdgcn_s_setprio(1);
    #pragma unroll
    for (int mi = 0; mi < 8; ++mi)
        acc[mi][1] = __builtin_amdgcn_mfma_f32_16x16x32_bf16(A[mi], Bv[1], acc[mi][1], 0, 0, 0);
    __builtin_amdgcn_s_setprio(0);
    Bv[3] = *(const s16x8*)(lb + bOff[3]);
    asm volatile("s_waitcnt lgkmcnt(1)" ::: "memory");
    __builtin_amdgcn_sched_barrier(0);
    __builtin_amdgcn_s_setprio(1);
    #pragma unroll
    for (int mi = 0; mi < 8; ++mi)
        acc[mi][2] = __builtin_amdgcn_mfma_f32_16x16x32_bf16(A[mi], Bv[2], acc[mi][2], 0, 0, 0);
    __builtin_amdgcn_s_setprio(0);
    asm volatile("s_waitcnt lgkmcnt(0)" ::: "memory");
    __builtin_amdgcn_sched_barrier(0);
    __builtin_amdgcn_s_setprio(1);
    #pragma unroll
    for (int mi = 0; mi < 8; ++mi)
        acc[mi][3] = __builtin_amdgcn_mfma_f32_16x16x32_bf16(A[mi], Bv[3], acc[mi][3], 0, 0, 0);
    __builtin_amdgcn_s_setprio(0);
}

// ---------------- GEMM1: x1 = gelu(spikes @ Wg^T + bg) * 32, bf16 out ----
// grid 768 1-D, XCD batch-major. 256 threads, 4 waves 2Mx2N, wave tile 128x64.
__global__ __launch_bounds__(256, 2) void gemm1_embed(
    const __hip_bfloat16* __restrict__ Sp,
    const __hip_bfloat16* __restrict__ We,
    const float* __restrict__ bEmb,
    const int* __restrict__ dateIdx,
    __hip_bfloat16* __restrict__ X1) {
    extern __shared__ __align__(16) char lds[];
    const int tid  = threadIdx.x;
    const int lane = tid & 63, wid = tid >> 6;
    const int wm = wid >> 1, wn = wid & 1;
    const int id   = blockIdx.x;             // 0..767
    const int xcd  = id & 7, slot = id >> 3; // slot 0..95
    const int b    = xcd * 4 + slot / 24;
    const int tile = slot % 24;
    const int m0   = (tile & 1) * 256;
    const int n0   = (tile >> 1) * 128;
    const int didx = dateIdx[b];
    const __hip_bfloat16* A  = Sp + (size_t)b * T_ * C_;
    const __hip_bfloat16* Bm = We + (size_t)didx * D_ * C_;
    const int KT = C_ / 32;                   // 12

    // per-thread staging sources (row-part precomputed; +kt*32 elems per tile)
    const __hip_bfloat16* aSrc[4]; const __hip_bfloat16* bSrc[2];
    int aDst[4], bDst[2];
    #pragma unroll
    for (int i = 0; i < 4; ++i) {
        int p = i * 256 + tid;                // 0..1023
        int row = p >> 2;
        int cl  = (p & 3) ^ ((row >> 1) & 3);
        aSrc[i] = A + (size_t)(m0 + row) * C_ + cl * 8;
        aDst[i] = (i * 256 + wid * 64) * 16;
    }
    #pragma unroll
    for (int i = 0; i < 2; ++i) {
        int p = i * 256 + tid;                // 0..511
        int row = p >> 2;
        int cl  = (p & 3) ^ ((row >> 1) & 3);
        bSrc[i] = Bm + (size_t)(n0 + row) * C_ + cl * 8;
        bDst[i] = 16384 + (i * 256 + wid * 64) * 16;
    }

    auto stage = [&](int kt, int buf) {
        char* lb0 = lds + buf * BUF1;
        int ko = kt * 32;
        #pragma unroll
        for (int i = 0; i < 4; ++i) gld_lds16(aSrc[i] + ko, lb0 + aDst[i]);
        #pragma unroll
        for (int i = 0; i < 2; ++i) gld_lds16(bSrc[i] + ko, lb0 + bDst[i]);
    };

    // fragment LDS offsets
    const int rl = lane & 15, g = lane >> 4;
    int aOff[8], bOff[4];
    #pragma unroll
    for (int mi = 0; mi < 8; ++mi) {
        int r = wm * 128 + mi * 16 + rl;
        aOff[mi] = r * 64 + (((g ^ (r >> 1)) & 3) << 4) + ((g & ~3) << 4);
    }
    #pragma unroll
    for (int ni = 0; ni < 4; ++ni) {
        int r = wn * 64 + ni * 16 + rl;
        bOff[ni] = 16384 + r * 64 + (((g ^ (r >> 1)) & 3) << 4) + ((g & ~3) << 4);
    }

    f32x4 acc[8][4] = {};
    stage(0, 0);
    stage(1, 1);
    for (int kt = 0; kt < KT - 2; ++kt) {
        stage(kt + 2, (kt + 2) % 3);
        asm volatile("s_waitcnt vmcnt(12)" ::: "memory");
        __builtin_amdgcn_s_barrier();
        const char* la = lds + (kt % 3) * BUF1;
        ktile32(la, la, aOff, bOff, acc);
        __builtin_amdgcn_s_barrier();
    }
    asm volatile("s_waitcnt vmcnt(6)" ::: "memory");
    __builtin_amdgcn_s_barrier();
    ktile32(lds + ((KT - 2) % 3) * BUF1, lds + ((KT - 2) % 3) * BUF1, aOff, bOff, acc);
    asm volatile("s_waitcnt vmcnt(0)" ::: "memory");
    __builtin_amdgcn_s_barrier();
    ktile32(lds + ((KT - 1) % 3) * BUF1, lds + ((KT - 1) % 3) * BUF1, aOff, bOff, acc);

    // epilogue: + bias, exact gelu, * 32, store bf16
    #pragma unroll
    for (int mi = 0; mi < 8; ++mi) {
        #pragma unroll
        for (int ni = 0; ni < 4; ++ni) {
            int col = n0 + wn * 64 + ni * 16 + rl;              // d
            float bg = bEmb[didx * D_ + col];
            #pragma unroll
            for (int r = 0; r < 4; ++r) {
                int row = m0 + wm * 128 + mi * 16 + g * 4 + r;  // t
                float v = acc[mi][ni][r] + bg;
                float gl = 0.5f * v * (1.0f + erff(v * 0.70710678118f)) * 32.0f;
                X1[((size_t)b * T_ + row) * D_ + col] = __float2bfloat16(gl);
            }
        }
    }
}

// ---------------- GEMM2 split-K: partial = patches(dslice) @ Wp(dslice)^T
// grid 256 1-D XCD batch-major: xcd owns 4 batches; per batch 8 blocks =
// {2 khalf x 4 ntiles}. Half kh covers d in [kh*768, kh*768+768), s = 0..3
// inner (L2 reuse of overlapping windows). kh=0 -> raw f32 into out;
// kh=1 -> bf16 partial into P1.
__global__ __launch_bounds__(512, 2) void gemm2_proj(
    const __hip_bfloat16* __restrict__ X1,
    const __hip_bfloat16* __restrict__ Wp,     // [H][KP] bf16
    float* __restrict__ outX,                  // partial kh=0
    __hip_bfloat16* __restrict__ P1) {         // partial kh=1
    extern __shared__ __align__(16) char lds[];
    const int tid  = threadIdx.x;
    const int lane = tid & 63, wid = tid >> 6;
    const int wm = wid >> 2, wn = wid & 3;
    const int id   = blockIdx.x;              // 0..255
    const int xcd  = id & 7, slot = id >> 3;  // slot 0..31
    const int b    = xcd * 4 + (slot >> 3);
    const int sub  = slot & 7;
    const int kh   = sub >> 2;                 // 0,1
    const int n0   = (sub & 3) * 256;
    const __hip_bfloat16* Xb = X1 + (size_t)b * T_ * D_;
    const int KT = 96;                         // K-tiles (32 wide) per half

    // staging sources: scalar per-tile offset koff = s*D + d0 (same for A & B)
    const __hip_bfloat16* aSrc[2]; const __hip_bfloat16* bSrc[2];
    int aDst[2], bDst[2];
    #pragma unroll
    for (int i = 0; i < 2; ++i) {
        int p = i * 512 + tid;                // 0..1023
        int row = p >> 2;
        int cl  = (p & 3) ^ ((row >> 1) & 3);
        int l = row < 255 ? row : 254;
        aSrc[i] = Xb + (size_t)(2 * l) * D_ + cl * 8;     // + koff per tile
        aDst[i] = (i * 512 + wid * 64) * 16;
        int rowB = p >> 2;
        bSrc[i] = Wp + (size_t)(n0 + rowB) * KP_ + cl * 8; // + koff per tile
        bDst[i] = 16384 + (i * 512 + wid * 64) * 16;
    }

    auto stage = [&](int gt, int buf) {
        char* lb0 = lds + buf * BUF2;
        int s  = gt & 3;
        int d0 = kh * 768 + (gt >> 2) * 32;
        int koff = s * D_ + d0;
        #pragma unroll
        for (int i = 0; i < 2; ++i) gld_lds16(aSrc[i] + koff, lb0 + aDst[i]);
        #pragma unroll
        for (int i = 0; i < 2; ++i) gld_lds16(bSrc[i] + koff, lb0 + bDst[i]);
    };

    const int rl = lane & 15, g = lane >> 4;
    int aOff[8], bOff[4];
    #pragma unroll
    for (int mi = 0; mi < 8; ++mi) {
        int r = wm * 128 + mi * 16 + rl;
        aOff[mi] = r * 64 + (((g ^ (r >> 1)) & 3) << 4) + ((g & ~3) << 4);
    }
    #pragma unroll
    for (int ni = 0; ni < 4; ++ni) {
        int r = wn * 64 + ni * 16 + rl;
        bOff[ni] = 16384 + r * 64 + (((g ^ (r >> 1)) & 3) << 4) + ((g & ~3) << 4);
    }

    f32x4 acc[8][4] = {};
    stage(0, 0);
    stage(1, 1);
    for (int kt = 0; kt < KT - 2; ++kt) {
        stage(kt + 2, (kt + 2) % 3);
        asm volatile("s_waitcnt vmcnt(8)" ::: "memory");
        __builtin_amdgcn_s_barrier();
        const char* la = lds + (kt % 3) * BUF2;
        ktile32(la, la, aOff, bOff, acc);
        __builtin_amdgcn_s_barrier();
    }
    asm volatile("s_waitcnt vmcnt(4)" ::: "memory");
    __builtin_amdgcn_s_barrier();
    ktile32(lds + ((KT - 2) % 3) * BUF2, lds + ((KT - 2) % 3) * BUF2, aOff, bOff, acc);
    asm volatile("s_waitcnt vmcnt(0)" ::: "memory");
    __builtin_amdgcn_s_barrier();
    ktile32(lds + ((KT - 1) % 3) * BUF2, lds + ((KT - 1) % 3) * BUF2, aOff, bOff, acc);

    // epilogue: raw partial store (bias/pos added in combine)
    #pragma unroll
    for (int mi = 0; mi < 8; ++mi) {
        #pragma unroll
        for (int ni = 0; ni < 4; ++ni) {
            int h = n0 + wn * 64 + ni * 16 + rl;
            #pragma unroll
            for (int r = 0; r < 4; ++r) {
                int l = wm * 128 + mi * 16 + g * 4 + r;
                if (l < L_) {
                    size_t o = ((size_t)b * L_ + l) * H_ + h;
                    if (kh == 0) outX[o] = acc[mi][ni][r];
                    else         P1[o]  = __float2bfloat16(acc[mi][ni][r]);
                }
            }
        }
    }
}

// ---------------- combine: out = p0(out) + p1 + b_proj + pos_table[ts] ----
// grid (255, 32), 256 threads; each thread one float4 (h = tid*4).
__global__ __launch_bounds__(256) void combine(
    const __hip_bfloat16* __restrict__ P1,
    const float* __restrict__ bProj,
    const float* __restrict__ posTab,
    const int* __restrict__ tsIn,
    float* __restrict__ outX) {
    const int l = blockIdx.x, b = blockIdx.y;
    const int h = threadIdx.x * 4;
    const size_t o4 = ((size_t)(b * L_ + l) * H_ + h) >> 2;
    const int tsv = tsIn[b * T_ + l];
    float4 v = reinterpret_cast<float4*>(outX)[o4];
    ushort4 u = reinterpret_cast<const ushort4*>(P1)[o4];
    union { unsigned ui; float f; } c0, c1, c2, c3;
    c0.ui = (unsigned)u.x << 16; c1.ui = (unsigned)u.y << 16;
    c2.ui = (unsigned)u.z << 16; c3.ui = (unsigned)u.w << 16;
    float4 bp = reinterpret_cast<const float4*>(bProj)[h >> 2];
    float4 pt = reinterpret_cast<const float4*>(posTab + (size_t)tsv * H_)[h >> 2];
    v.x += c0.f + bp.x + pt.x;
    v.y += c1.f + bp.y + pt.y;
    v.z += c2.f + bp.z + pt.z;
    v.w += c3.f + bp.w + pt.w;
    reinterpret_cast<float4*>(outX)[o4] = v;
}

extern "C" void kernel_launch(void* const* d_in, const int* in_sizes, int n_in,
                              void* d_out, int out_size, void* d_ws, size_t ws_size,
                              hipStream_t stream) {
    (void)in_sizes; (void)n_in; (void)out_size; (void)ws_size;
    const float* spikes  = (const float*)d_in[0];
    const int*   smask   = (const int*)d_in[1];
    const int*   sts     = (const int*)d_in[2];
    const int*   dateIdx = (const int*)d_in[3];
    const float* Wemb    = (const float*)d_in[4];
    const float* bEmb    = (const float*)d_in[5];
    const float* Wproj   = (const float*)d_in[6];
    const float* bProj   = (const float*)d_in[7];
    const float* posTab  = (const float*)d_in[8];
    float* out = (float*)d_out;

    // workspace layout (bytes):
    // X1 bf16   [B][T][D]  : 50331648                 @ 0
    // SpB bf16  [B][T][C]  : 12582912                 @ 50331648
    // WeB bf16  [ND][D][C] : 18874368                 @ 62914560  (dead after gemm1)
    //   P1 bf16 [B][L][H]  : 16711680                 @ 62914560  (aliases WeB)
    // WpB bf16  [H][KP]    : 12582912                 @ 81788928
    char* ws = (char*)d_ws;
    __hip_bfloat16* X1  = (__hip_bfloat16*)(ws);
    __hip_bfloat16* SpB = (__hip_bfloat16*)(ws + 50331648);
    __hip_bfloat16* WeB = (__hip_bfloat16*)(ws + 62914560);
    __hip_bfloat16* P1  = (__hip_bfloat16*)(ws + 62914560);
    __hip_bfloat16* WpB = (__hip_bfloat16*)(ws + 81788928);

    static int smem_set = 0;
    if (!smem_set) {
        hipFuncSetAttribute((const void*)gemm1_embed,
                            hipFuncAttributeMaxDynamicSharedMemorySize, 3 * BUF1);
        hipFuncSetAttribute((const void*)gemm2_proj,
                            hipFuncAttributeMaxDynamicSharedMemorySize, 3 * BUF2);
        smem_set = 1;
    }

    prep<<<21536, 256, 0, stream>>>(spikes, Wemb, Wproj, smask, sts,
                                    SpB, WeB, WpB, out);

    gemm1_embed<<<768, 256, 3 * BUF1, stream>>>(SpB, WeB, bEmb, dateIdx, X1);

    gemm2_proj<<<256, 512, 3 * BUF2, stream>>>(X1, WpB, out, P1);

    dim3 gc(L_, B_);
    combine<<<gc, 256, 0, stream>>>(P1, bProj, posTab, sts, out);
}

// Round 6
// 196.696 us; speedup vs baseline: 1.0300x; 1.0300x over previous
//
#include <hip/hip_runtime.h>
#include <hip/hip_bf16.h>

// Problem constants
#define B_    32
#define T_    512
#define C_    384
#define D_    1536      // C*MULT
#define H_    1024
#define L_    255       // (T-SIZE)/STRIDE + 1
#define KP_   6144      // SIZE*D
#define ND_   16

// 8-wave 256x256 tile, BK=64, wave tile 128x64 (2M x 4N).
// LDS: 2 buffers x (A 32KB + B 32KB) = 128KB. 4 phases per K64 tile
// (one C-quadrant each, 16 MFMA), barriers between phases so LDS-read
// drain overlaps MFMA across waves. Counted vmcnt(8): the newest 8 glds
// are always the NEXT tile's -> loads in flight across barriers.
// Staging ring (race-free by construction):
//   B(u+1) issued in P1 window -> region's readers done one iter ago
//   A(u+2) issued in P4 window -> A readers completed at P3 close barrier
#define TILEB 65536
#define LDS_TOT 131072

using f32x4 = __attribute__((ext_vector_type(4))) float;
using s16x8 = __attribute__((ext_vector_type(8))) short;

__device__ __forceinline__ void gld_lds16(const void* g, void* l) {
    __builtin_amdgcn_global_load_lds(
        (const __attribute__((address_space(1))) void*)g,
        (__attribute__((address_space(3))) void*)l,
        16, 0, 0);
}

__device__ __forceinline__ f32x4 MFMA(s16x8 a, s16x8 b, f32x4 c) {
    return __builtin_amdgcn_mfma_f32_16x16x32_bf16(a, b, c, 0, 0, 0);
}

// ------------- prep: all f32->bf16 conversions + mask/ts, one launch ----
__global__ __launch_bounds__(256) void prep(
    const float* __restrict__ sp, const float* __restrict__ we,
    const float* __restrict__ wp, const int* __restrict__ mIn,
    const int* __restrict__ tIn,
    __hip_bfloat16* __restrict__ spB, __hip_bfloat16* __restrict__ weB,
    __hip_bfloat16* __restrict__ wpB, float* __restrict__ out) {
    int id = blockIdx.x * 256 + threadIdx.x;
    const float* src; __hip_bfloat16* dst; int idx;
    if (id < 1572864)       { src = sp; dst = spB; idx = id; }
    else if (id < 3932160)  { src = we; dst = weB; idx = id - 1572864; }
    else if (id < 5505024)  { src = wp; dst = wpB; idx = id - 3932160; }
    else {
        int i = id - 5505024;
        if (i < B_ * L_) {
            int b = i / L_, l = i % L_;
            const int* mb = mIn + b * T_ + 2 * l;
            int m = mb[0] * mb[1] * mb[2] * mb[3];
            const size_t offM = (size_t)B_ * L_ * H_;
            out[offM + i] = (float)m;
            out[offM + (size_t)B_ * L_ + i] = (float)tIn[b * T_ + l];
        }
        return;
    }
    float4 v = reinterpret_cast<const float4*>(src)[idx];
    __hip_bfloat16 o[4] = {__float2bfloat16(v.x), __float2bfloat16(v.y),
                           __float2bfloat16(v.z), __float2bfloat16(v.w)};
    reinterpret_cast<ushort4*>(dst)[idx] = *reinterpret_cast<ushort4*>(o);
}

// --- one K64 iteration: 4 phases, quadrant order A0B0, A0B1, A1B0, A1B1 ---
template <class FB, class FA>
__device__ __forceinline__ void iter_k64(const char* bufA, const char* bufB,
                                         const int (&aB)[8], const int (&bB)[4],
                                         int c0, int c1,
                                         f32x4 (&acc)[8][4], bool last,
                                         FB&& stB, FA&& stA) {
    s16x8 A[4][2], B0[2][2], B1[2][2];
    // ---- P1: stage B(next), tile-entry wait, read A0+B0, MFMA A0*B0
    stB();
    if (last) { asm volatile("s_waitcnt vmcnt(0)" ::: "memory"); }
    else      { asm volatile("s_waitcnt vmcnt(8)" ::: "memory"); }
    __builtin_amdgcn_s_barrier();
    #pragma unroll
    for (int mi = 0; mi < 4; ++mi) {
        A[mi][0] = *(const s16x8*)(bufA + aB[mi] + c0);
        A[mi][1] = *(const s16x8*)(bufA + aB[mi] + c1);
    }
    #pragma unroll
    for (int ni = 0; ni < 2; ++ni) {
        B0[ni][0] = *(const s16x8*)(bufB + bB[ni] + c0);
        B0[ni][1] = *(const s16x8*)(bufB + bB[ni] + c1);
    }
    asm volatile("s_waitcnt lgkmcnt(0)" ::: "memory");
    __builtin_amdgcn_sched_barrier(0);
    __builtin_amdgcn_s_setprio(1);
    #pragma unroll
    for (int mi = 0; mi < 4; ++mi)
        #pragma unroll
        for (int ni = 0; ni < 2; ++ni)
            #pragma unroll
            for (int ks = 0; ks < 2; ++ks)
                acc[mi][ni] = MFMA(A[mi][ks], B0[ni][ks], acc[mi][ni]);
    __builtin_amdgcn_s_setprio(0);
    __builtin_amdgcn_s_barrier();
    // ---- P2: read B1, MFMA A0*B1
    #pragma unroll
    for (int ni = 0; ni < 2; ++ni) {
        B1[ni][0] = *(const s16x8*)(bufB + bB[2 + ni] + c0);
        B1[ni][1] = *(const s16x8*)(bufB + bB[2 + ni] + c1);
    }
    __builtin_amdgcn_s_barrier();
    asm volatile("s_waitcnt lgkmcnt(0)" ::: "memory");
    __builtin_amdgcn_sched_barrier(0);
    __builtin_amdgcn_s_setprio(1);
    #pragma unroll
    for (int mi = 0; mi < 4; ++mi)
        #pragma unroll
        for (int ni = 0; ni < 2; ++ni)
            #pragma unroll
            for (int ks = 0; ks < 2; ++ks)
                acc[mi][2 + ni] = MFMA(A[mi][ks], B1[ni][ks], acc[mi][2 + ni]);
    __builtin_amdgcn_s_setprio(0);
    __builtin_amdgcn_s_barrier();
    // ---- P3: read A1 (overwrite A regs), MFMA A1*B0
    #pragma unroll
    for (int mi = 0; mi < 4; ++mi) {
        A[mi][0] = *(const s16x8*)(bufA + aB[4 + mi] + c0);
        A[mi][1] = *(const s16x8*)(bufA + aB[4 + mi] + c1);
    }
    __builtin_amdgcn_s_barrier();
    asm volatile("s_waitcnt lgkmcnt(0)" ::: "memory");
    __builtin_amdgcn_sched_barrier(0);
    __builtin_amdgcn_s_setprio(1);
    #pragma unroll
    for (int mi = 0; mi < 4; ++mi)
        #pragma unroll
        for (int ni = 0; ni < 2; ++ni)
            #pragma unroll
            for (int ks = 0; ks < 2; ++ks)
                acc[4 + mi][ni] = MFMA(A[mi][ks], B0[ni][ks], acc[4 + mi][ni]);
    __builtin_amdgcn_s_setprio(0);
    __builtin_amdgcn_s_barrier();   // all A reads of this tile complete
    // ---- P4: stage A(next2) into just-freed A region, MFMA A1*B1
    stA();
    __builtin_amdgcn_s_setprio(1);
    #pragma unroll
    for (int mi = 0; mi < 4; ++mi)
        #pragma unroll
        for (int ni = 0; ni < 2; ++ni)
            #pragma unroll
            for (int ks = 0; ks < 2; ++ks)
                acc[4 + mi][2 + ni] = MFMA(A[mi][ks], B1[ni][ks], acc[4 + mi][2 + ni]);
    __builtin_amdgcn_s_setprio(0);
    // no closing barrier: next iteration's P1 vmcnt+barrier covers it
}

// ---------------- GEMM1: x1 = gelu(spikes @ Wg^T + bg) * 32, bf16 out ----
// grid 384 1-D XCD-swizzled; BM=256(t) BN=256(d), KT2 = 6 K64-tiles.
__global__ __launch_bounds__(512, 2) void gemm1_embed(
    const __hip_bfloat16* __restrict__ Sp,
    const __hip_bfloat16* __restrict__ We,
    const float* __restrict__ bEmb,
    const int* __restrict__ dateIdx,
    __hip_bfloat16* __restrict__ X1) {
    extern __shared__ __align__(16) char lds[];
    const int tid  = threadIdx.x;
    const int lane = tid & 63, wid = tid >> 6;
    const int wm = wid >> 2, wn = wid & 3;
    const int id   = blockIdx.x;              // 0..383
    const int xcd  = id & 7, slot = id >> 3;  // slot 0..47
    const int b    = xcd * 4 + slot / 12;
    const int tile = slot % 12;
    const int m0   = (tile & 1) * 256;
    const int n0   = (tile >> 1) * 256;
    const int didx = dateIdx[b];
    const __hip_bfloat16* Ab = Sp + (size_t)b * T_ * C_;
    const __hip_bfloat16* Bm = We + (size_t)didx * D_ * C_;
    const int KT2 = C_ / 64;                  // 6

    // staging pointers: 2048 chunks per operand tile, 4 glds/thread each
    const __hip_bfloat16* aP[4]; const __hip_bfloat16* bP[4]; int sD[4];
    #pragma unroll
    for (int i = 0; i < 4; ++i) {
        int p = i * 512 + tid;
        int row = p >> 3;
        int cl  = (p & 7) ^ (row & 7);
        aP[i] = Ab + (size_t)(m0 + row) * C_ + cl * 8;
        bP[i] = Bm + (size_t)(n0 + row) * C_ + cl * 8;
        sD[i] = (i * 512 + wid * 64) * 16;
    }
    auto stAf = [&](int kt, char* dst) {
        int ko = kt * 64;
        #pragma unroll
        for (int i = 0; i < 4; ++i) gld_lds16(aP[i] + ko, dst + sD[i]);
    };
    auto stBf = [&](int kt, char* dst) {
        int ko = kt * 64;
        #pragma unroll
        for (int i = 0; i < 4; ++i) gld_lds16(bP[i] + ko, dst + sD[i]);
    };

    // fragment bases
    const int rl = lane & 15, g = lane >> 4;
    const int c0 = ((g ^ (rl & 7)) << 4), c1 = (((4 + g) ^ (rl & 7)) << 4);
    int aB[8], bB[4];
    #pragma unroll
    for (int mi = 0; mi < 8; ++mi) aB[mi] = (wm * 128 + mi * 16 + rl) * 128;
    #pragma unroll
    for (int ni = 0; ni < 4; ++ni) bB[ni] = (wn * 64 + ni * 16 + rl) * 128;

    f32x4 acc[8][4] = {};
    stAf(0, lds);
    stBf(0, lds + 32768);
    stAf(1, lds + TILEB);
    for (int u = 0; u < KT2; ++u) {
        const char* bA = lds + (u & 1) * TILEB;
        iter_k64(bA, bA + 32768, aB, bB, c0, c1, acc, u == KT2 - 1,
                 [&]{ if (u + 1 < KT2) stBf(u + 1, lds + ((u + 1) & 1) * TILEB + 32768); },
                 [&]{ if (u + 2 < KT2) stAf(u + 2, lds + (u & 1) * TILEB); });
    }

    // epilogue: + bias, exact gelu, * 32, store bf16
    #pragma unroll
    for (int mi = 0; mi < 8; ++mi) {
        #pragma unroll
        for (int ni = 0; ni < 4; ++ni) {
            int col = n0 + wn * 64 + ni * 16 + rl;               // d
            float bg = bEmb[didx * D_ + col];
            #pragma unroll
            for (int r = 0; r < 4; ++r) {
                int row = m0 + wm * 128 + mi * 16 + g * 4 + r;   // t
                float v = acc[mi][ni][r] + bg;
                float gl = 0.5f * v * (1.0f + erff(v * 0.70710678118f)) * 32.0f;
                X1[((size_t)b * T_ + row) * D_ + col] = __float2bfloat16(gl);
            }
        }
    }
}

// ---------------- GEMM2 split-K x2: partial = patches(dslice) @ Wp^T -----
// grid 256 1-D XCD batch-major; BM=256(l) BN=256(h), 48 K64-tiles per half.
// K-order s-inner (kt&3) for L2 reuse of overlapping windows.
__global__ __launch_bounds__(512, 2) void gemm2_proj(
    const __hip_bfloat16* __restrict__ X1,
    const __hip_bfloat16* __restrict__ Wp,
    float* __restrict__ outX,                  // partial kh=0
    __hip_bfloat16* __restrict__ P1) {         // partial kh=1
    extern __shared__ __align__(16) char lds[];
    const int tid  = threadIdx.x;
    const int lane = tid & 63, wid = tid >> 6;
    const int wm = wid >> 2, wn = wid & 3;
    const int id   = blockIdx.x;               // 0..255
    const int xcd  = id & 7, slot = id >> 3;   // 0..31
    const int b    = xcd * 4 + (slot >> 3);
    const int sub  = slot & 7;
    const int kh   = sub >> 2;
    const int n0   = (sub & 3) * 256;
    const __hip_bfloat16* Xb = X1 + (size_t)b * T_ * D_;
    const int KT2 = 48;

    const __hip_bfloat16* aP[4]; const __hip_bfloat16* bP[4]; int sD[4];
    #pragma unroll
    for (int i = 0; i < 4; ++i) {
        int p = i * 512 + tid;
        int row = p >> 3;
        int cl  = (p & 7) ^ (row & 7);
        int l = row < 255 ? row : 254;
        aP[i] = Xb + (size_t)(2 * l) * D_ + cl * 8;
        bP[i] = Wp + (size_t)(n0 + row) * KP_ + cl * 8;
        sD[i] = (i * 512 + wid * 64) * 16;
    }
    auto kofs = [&](int kt) { return (kt & 3) * D_ + kh * 768 + (kt >> 2) * 64; };
    auto stAf = [&](int kt, char* dst) {
        int ko = kofs(kt);
        #pragma unroll
        for (int i = 0; i < 4; ++i) gld_lds16(aP[i] + ko, dst + sD[i]);
    };
    auto stBf = [&](int kt, char* dst) {
        int ko = kofs(kt);
        #pragma unroll
        for (int i = 0; i < 4; ++i) gld_lds16(bP[i] + ko, dst + sD[i]);
    };

    const int rl = lane & 15, g = lane >> 4;
    const int c0 = ((g ^ (rl & 7)) << 4), c1 = (((4 + g) ^ (rl & 7)) << 4);
    int aB[8], bB[4];
    #pragma unroll
    for (int mi = 0; mi < 8; ++mi) aB[mi] = (wm * 128 + mi * 16 + rl) * 128;
    #pragma unroll
    for (int ni = 0; ni < 4; ++ni) bB[ni] = (wn * 64 + ni * 16 + rl) * 128;

    f32x4 acc[8][4] = {};
    stAf(0, lds);
    stBf(0, lds + 32768);
    stAf(1, lds + TILEB);
    for (int u = 0; u < KT2; ++u) {
        const char* bA = lds + (u & 1) * TILEB;
        iter_k64(bA, bA + 32768, aB, bB, c0, c1, acc, u == KT2 - 1,
                 [&]{ if (u + 1 < KT2) stBf(u + 1, lds + ((u + 1) & 1) * TILEB + 32768); },
                 [&]{ if (u + 2 < KT2) stAf(u + 2, lds + (u & 1) * TILEB); });
    }

    // epilogue: raw partial store (bias/pos added in combine)
    #pragma unroll
    for (int mi = 0; mi < 8; ++mi) {
        #pragma unroll
        for (int ni = 0; ni < 4; ++ni) {
            int h = n0 + wn * 64 + ni * 16 + rl;
            #pragma unroll
            for (int r = 0; r < 4; ++r) {
                int l = wm * 128 + mi * 16 + g * 4 + r;
                if (l < L_) {
                    size_t o = ((size_t)b * L_ + l) * H_ + h;
                    if (kh == 0) outX[o] = acc[mi][ni][r];
                    else         P1[o]  = __float2bfloat16(acc[mi][ni][r]);
                }
            }
        }
    }
}

// ---------------- combine: out = p0(out) + p1 + b_proj + pos_table[ts] ----
__global__ __launch_bounds__(256) void combine(
    const __hip_bfloat16* __restrict__ P1,
    const float* __restrict__ bProj,
    const float* __restrict__ posTab,
    const int* __restrict__ tsIn,
    float* __restrict__ outX) {
    const int l = blockIdx.x, b = blockIdx.y;
    const int h = threadIdx.x * 4;
    const size_t o4 = ((size_t)(b * L_ + l) * H_ + h) >> 2;
    const int tsv = tsIn[b * T_ + l];
    float4 v = reinterpret_cast<float4*>(outX)[o4];
    ushort4 u = reinterpret_cast<const ushort4*>(P1)[o4];
    union { unsigned ui; float f; } c0, c1, c2, c3;
    c0.ui = (unsigned)u.x << 16; c1.ui = (unsigned)u.y << 16;
    c2.ui = (unsigned)u.z << 16; c3.ui = (unsigned)u.w << 16;
    float4 bp = reinterpret_cast<const float4*>(bProj)[h >> 2];
    float4 pt = reinterpret_cast<const float4*>(posTab + (size_t)tsv * H_)[h >> 2];
    v.x += c0.f + bp.x + pt.x;
    v.y += c1.f + bp.y + pt.y;
    v.z += c2.f + bp.z + pt.z;
    v.w += c3.f + bp.w + pt.w;
    reinterpret_cast<float4*>(outX)[o4] = v;
}

extern "C" void kernel_launch(void* const* d_in, const int* in_sizes, int n_in,
                              void* d_out, int out_size, void* d_ws, size_t ws_size,
                              hipStream_t stream) {
    (void)in_sizes; (void)n_in; (void)out_size; (void)ws_size;
    const float* spikes  = (const float*)d_in[0];
    const int*   smask   = (const int*)d_in[1];
    const int*   sts     = (const int*)d_in[2];
    const int*   dateIdx = (const int*)d_in[3];
    const float* Wemb    = (const float*)d_in[4];
    const float* bEmb    = (const float*)d_in[5];
    const float* Wproj   = (const float*)d_in[6];
    const float* bProj   = (const float*)d_in[7];
    const float* posTab  = (const float*)d_in[8];
    float* out = (float*)d_out;

    // workspace layout (bytes):
    // X1 bf16   [B][T][D]  : 50331648                 @ 0
    // SpB bf16  [B][T][C]  : 12582912                 @ 50331648
    // WeB bf16  [ND][D][C] : 18874368                 @ 62914560  (dead after gemm1)
    //   P1 bf16 [B][L][H]  : 16711680                 @ 62914560  (aliases WeB)
    // WpB bf16  [H][KP]    : 12582912                 @ 81788928
    char* ws = (char*)d_ws;
    __hip_bfloat16* X1  = (__hip_bfloat16*)(ws);
    __hip_bfloat16* SpB = (__hip_bfloat16*)(ws + 50331648);
    __hip_bfloat16* WeB = (__hip_bfloat16*)(ws + 62914560);
    __hip_bfloat16* P1  = (__hip_bfloat16*)(ws + 62914560);
    __hip_bfloat16* WpB = (__hip_bfloat16*)(ws + 81788928);

    hipFuncSetAttribute((const void*)gemm1_embed,
                        hipFuncAttributeMaxDynamicSharedMemorySize, LDS_TOT);
    hipFuncSetAttribute((const void*)gemm2_proj,
                        hipFuncAttributeMaxDynamicSharedMemorySize, LDS_TOT);

    prep<<<21536, 256, 0, stream>>>(spikes, Wemb, Wproj, smask, sts,
                                    SpB, WeB, WpB, out);

    gemm1_embed<<<384, 512, LDS_TOT, stream>>>(SpB, WeB, bEmb, dateIdx, X1);

    gemm2_proj<<<256, 512, LDS_TOT, stream>>>(X1, WpB, out, P1);

    dim3 gc(L_, B_);
    combine<<<gc, 256, 0, stream>>>(P1, bProj, posTab, sts, out);
}